// Round 1
// baseline (123.422 us; speedup 1.0000x reference)
//
#include <hip/hip_runtime.h>
#include <hip/hip_bf16.h>

#define IN_CH 256
#define OUT_CH 256
#define LATENT 512
#define MSCALE (1.0f / 16.0f)   // 1/sqrt(256)

typedef __attribute__((ext_vector_type(8)))  short bf16x8;
typedef __attribute__((ext_vector_type(16))) float f32x16;
typedef unsigned short u16;

__device__ __forceinline__ u16 f2bf(float f) {
  unsigned int x = __float_as_uint(f);
  x += 0x7fffu + ((x >> 16) & 1u);   // round-to-nearest-even
  return (u16)(x >> 16);
}

// ---- async global->LDS, 16B per lane. dst must be wave-uniform; HW deposits
// at dst + lane*16. Fallback: explicit reg staging (same addresses).
__device__ __forceinline__ void gload_lds16(const u16* g, u16* l) {
#if defined(__has_builtin) && __has_builtin(__builtin_amdgcn_global_load_lds)
  __builtin_amdgcn_global_load_lds(
      (const __attribute__((address_space(1))) unsigned int*)g,
      (__attribute__((address_space(3))) unsigned int*)l, 16, 0, 0);
#else
  int lane = __builtin_amdgcn_mbcnt_hi(~0u, __builtin_amdgcn_mbcnt_lo(~0u, 0));
  ((uint4*)l)[lane] = *(const uint4*)g;
#endif
}

// ---------------- kernel 1: style -> mod[b][i] = (1+style)*SCALE ----------
__global__ void k_style(const float* __restrict__ w, const float* __restrict__ sw,
                        const float* __restrict__ sb, float* __restrict__ mod) {
  __shared__ float ws[LATENT];
  const int b = blockIdx.x, tid = threadIdx.x;
  ws[tid] = w[b * LATENT + tid];
  ws[tid + 256] = w[b * LATENT + 256 + tid];
  __syncthreads();
  const float4* sr = (const float4*)(sw + (size_t)tid * LATENT);
  const float4* wr = (const float4*)ws;
  float s = 0.f;
#pragma unroll 8
  for (int l = 0; l < LATENT / 4; ++l) {
    float4 a = sr[l], c = wr[l];
    s += a.x * c.x + a.y * c.y + a.z * c.z + a.w * c.w;
  }
  mod[b * IN_CH + tid] = (1.0f + s + sb[tid]) * MSCALE;
}

// -------- kernel 2: wsq[o][i] = sum_9 weight^2 ; wb[t][o][i] = bf16(weight) --
__global__ void k_wsq(const float* __restrict__ weight, float* __restrict__ wsq,
                      u16* __restrict__ wb) {
  const int o = blockIdx.x, i = threadIdx.x;
  const float* wp = weight + ((size_t)o * IN_CH + i) * 9;
  float s = 0.f;
#pragma unroll
  for (int t = 0; t < 9; ++t) {
    float v = wp[t];
    s += v * v;
    wb[((size_t)t * OUT_CH + o) * IN_CH + i] = f2bf(v);
  }
  wsq[o * IN_CH + i] = s;
}

// -------- kernel 3: demod[b][o] = rsqrt( sum_i mod^2 * wsq + 1e-8 ) --------
__global__ void k_demod(const float* __restrict__ mod, const float* __restrict__ wsq,
                        float* __restrict__ demod) {
  __shared__ float m2[IN_CH];
  const int b = blockIdx.x, tid = threadIdx.x;
  float m = mod[b * IN_CH + tid];
  m2[tid] = m * m;                     // = (SCALE*(1+style))^2
  __syncthreads();
  float s = 1e-8f;
  const float* wr = wsq + (size_t)tid * IN_CH;
#pragma unroll 4
  for (int i = 0; i < IN_CH; ++i) s += m2[i] * wr[i];
  demod[b * OUT_CH + tid] = rsqrtf(s);
}

// -------- kernel 4: xs[b][ph][pw][i] = bf16(x[b][i][h][w]*mod), zero-padded --
__global__ void k_pad(const float* __restrict__ x, const float* __restrict__ mod,
                      u16* __restrict__ xs) {
  const int bid = blockIdx.x;
  const int b = bid / 66, pr = bid - b * 66;
  const int i = threadIdx.x;
  u16* row = xs + (size_t)((b * 66 + pr) * 66) * IN_CH;
  if (pr == 0 || pr == 65) {
    for (int c = 0; c < 66; ++c) row[c * IN_CH + i] = 0;
  } else {
    const float ms = mod[b * IN_CH + i];
    const float* xp = x + (size_t)((b * IN_CH + i) * 64 + (pr - 1)) * 64;
    row[i] = 0;
    row[65 * IN_CH + i] = 0;
#pragma unroll 4
    for (int c = 0; c < 64; ++c) row[(c + 1) * IN_CH + i] = f2bf(xp[c] * ms);
  }
}

// -------- kernel 5: 9-tap implicit-GEMM conv, mfma_f32_32x32x16_bf16 -------
// block: 4 waves; tile 64 O x 8 rows x 64 px. wave w -> rows 2w,2w+1.
// LDS X: 10 rows x 66 cols x 32 ich (quad-swizzled). W: 9 taps x 64 o x 32 ich.
__global__ __launch_bounds__(256, 2)
void k_conv(const u16* __restrict__ xs, const u16* __restrict__ wb,
            const float* __restrict__ demod, float* __restrict__ out) {
  __shared__ __align__(16) u16 xlds[10 * 66 * 32];  // 42240 B
  __shared__ __align__(16) u16 wlds[9 * 64 * 32];   // 36864 B

  const int tid = threadIdx.x;
  const int lane = tid & 63;
  const int wid = tid >> 6;
  const int ol = lane & 31;
  const int hi = lane >> 5;
  const int aswz = (ol >> 1) & 3;

  const int bid = blockIdx.x;
  const int sbid = ((bid & 7) << 6) | (bid >> 3);   // bijective XCD swizzle (512 = 8*64)
  const int otile = (sbid & 3) << 6;
  const int hbase = ((sbid >> 2) & 7) << 3;
  const int b = sbid >> 5;

  f32x16 acc[2][4] = {};

  const u16* xsb = xs + (size_t)((b * 66 + hbase) * 66) * IN_CH;

  for (int ic = 0; ic < 8; ++ic) {
    const int ibase = ic * 32;
    __syncthreads();   // previous chunk's LDS reads complete

    // ---- stage X: 10*66 cells * 4 quads = 2640 quads of 16B
#pragma unroll
    for (int it = 0; it < 10; ++it) {
      int q = it * 256 + tid;
      int cq = q >> 2, s = q & 3;
      int c = cq % 66;
      int g = s ^ ((c >> 1) & 3);                  // pre-swizzled source group
      gload_lds16(xsb + (size_t)cq * IN_CH + ibase + g * 8,
                  xlds + (size_t)(it * 256 + wid * 64) * 8);
    }
    if (tid < 80) {
      int q = 2560 + tid;
      int cq = q >> 2, s = q & 3;
      int c = cq % 66;
      int g = s ^ ((c >> 1) & 3);
      gload_lds16(xsb + (size_t)cq * IN_CH + ibase + g * 8,
                  xlds + (size_t)(2560 + wid * 64) * 8);
    }
    // ---- stage W: 9*64 cells * 4 quads = 2304 quads
#pragma unroll
    for (int it = 0; it < 9; ++it) {
      int q = it * 256 + tid;
      int cell = q >> 2, s = q & 3;
      int o = cell & 63;
      int g = s ^ ((o >> 1) & 3);
      gload_lds16(wb + (size_t)((cell >> 6) * 256 + otile + o) * IN_CH + ibase + g * 8,
                  wlds + (size_t)(it * 256 + wid * 64) * 8);
    }
    __syncthreads();   // drains vmcnt(0): staged data visible

    // ---- compute: 9 taps x 2 k-steps x (2 osub x 4 psub) MFMAs
#pragma unroll
    for (int t = 0; t < 9; ++t) {
      const int dh = t / 3;
      const int dw = t - dh * 3;
#pragma unroll
      for (int k = 0; k < 2; ++k) {
        const int g = 2 * k + hi;
        bf16x8 a0 = *(const bf16x8*)(wlds + (size_t)((t * 64 + ol) * 4 + (g ^ aswz)) * 8);
        bf16x8 a1 = *(const bf16x8*)(wlds + (size_t)((t * 64 + 32 + ol) * 4 + (g ^ aswz)) * 8);
#pragma unroll
        for (int ps = 0; ps < 4; ++ps) {
          const int r = 2 * wid + (ps >> 1) + dh;          // padded local row 0..9
          const int c = (ps & 1) * 32 + ol + dw;           // padded col 0..65
          bf16x8 bf = *(const bf16x8*)(xlds + (size_t)((r * 66 + c) * 4 + (g ^ ((c >> 1) & 3))) * 8);
          acc[0][ps] = __builtin_amdgcn_mfma_f32_32x32x16_bf16(a0, bf, acc[0][ps], 0, 0, 0);
          acc[1][ps] = __builtin_amdgcn_mfma_f32_32x32x16_bf16(a1, bf, acc[1][ps], 0, 0, 0);
        }
      }
    }
  }

  // ---- epilogue: out = acc * demod[b][o]
  const float* dmb = demod + b * OUT_CH + otile;
  float* outb = out + (size_t)b * OUT_CH * 4096;
#pragma unroll
  for (int os = 0; os < 2; ++os) {
    float dm[16];
#pragma unroll
    for (int qd = 0; qd < 4; ++qd) {
      float4 d4 = *(const float4*)(dmb + os * 32 + qd * 8 + hi * 4);
      dm[qd * 4 + 0] = d4.x; dm[qd * 4 + 1] = d4.y;
      dm[qd * 4 + 2] = d4.z; dm[qd * 4 + 3] = d4.w;
    }
#pragma unroll
    for (int ps = 0; ps < 4; ++ps) {
      const int prow = hbase + 2 * wid + (ps >> 1);
      const int col = (ps & 1) * 32 + ol;
#pragma unroll
      for (int rr = 0; rr < 16; ++rr) {
        const int orow = (rr & 3) + 8 * (rr >> 2) + 4 * hi;  // C/D row map (m74/m101)
        const int o = otile + os * 32 + orow;
        outb[(size_t)o * 4096 + prow * 64 + col] = acc[os][ps][rr] * dm[rr];
      }
    }
  }
}

extern "C" void kernel_launch(void* const* d_in, const int* in_sizes, int n_in,
                              void* d_out, int out_size, void* d_ws, size_t ws_size,
                              hipStream_t stream) {
  const float* x  = (const float*)d_in[0];   // [16,256,64,64]
  const float* w  = (const float*)d_in[1];   // [16,512]
  const float* sw = (const float*)d_in[2];   // [256,512]
  const float* sb = (const float*)d_in[3];   // [256]
  const float* wt = (const float*)d_in[4];   // [1,256,256,3,3]
  float* out = (float*)d_out;

  char* ws = (char*)d_ws;
  u16*   xs    = (u16*)(ws);                  // 35,684,352 B : padded bf16 x*mod
  u16*   wb    = (u16*)(ws + 35684352);       //  1,179,648 B : bf16 weights [t][o][i]
  float* mod   = (float*)(ws + 36864000);     //     16,384 B
  float* demod = (float*)(ws + 36880384);     //     16,384 B
  float* wsq   = (float*)(ws + 36896768);     //    262,144 B   (total 37,158,912)
  if (ws_size < 37158912u) return;            // visible failure instead of OOB

  k_style<<<16, 256, 0, stream>>>(w, sw, sb, mod);
  k_wsq  <<<256, 256, 0, stream>>>(wt, wsq, wb);
  k_demod<<<16, 256, 0, stream>>>(mod, wsq, demod);
  k_pad  <<<16 * 66, 256, 0, stream>>>(x, mod, xs);
  k_conv <<<512, 256, 0, stream>>>(xs, wb, demod, out);
}